// Round 7
// baseline (321.320 us; speedup 1.0000x reference)
//
#include <hip/hip_runtime.h>

static constexpr int D = 128;
static constexpr int PS = 32;   // pool slices per graph

typedef __attribute__((ext_vector_type(8))) short short8;
typedef __attribute__((ext_vector_type(4))) float f32x4;

__device__ inline ushort f2bf(float f) {
  union { float f; unsigned u; } v; v.f = f;
  unsigned r = v.u + 0x7FFF + ((v.u >> 16) & 1);
  return (ushort)(r >> 16);
}
__device__ inline float bf2f_lo(unsigned p) {
  union { unsigned u; float f; } v; v.u = p << 16; return v.f;
}
__device__ inline float bf2f_hi(unsigned p) {
  union { unsigned u; float f; } v; v.u = p & 0xFFFF0000u; return v.f;
}

struct WPtrs { const float* s[6]; ushort* d[6]; };

// fused prep: [0,nxb) cvt x -> bf16 ; [nxb,nxb+96) cvt weights ; rest: dst histogram
__global__ __launch_bounds__(256) void k_prep(const float* __restrict__ x, ushort* __restrict__ xb, WPtrs p,
                                              const int* __restrict__ dst, int* __restrict__ hist,
                                              int n4x, int E) {
  int b = blockIdx.x, tid = threadIdx.x;
  int nxb = (n4x + 255) / 256;
  if (b < nxb) {
    int i = b * 256 + tid;
    if (i < n4x) {
      float4 v = *(const float4*)&x[i * 4];
      ushort4 o;
      o.x = f2bf(v.x); o.y = f2bf(v.y); o.z = f2bf(v.z); o.w = f2bf(v.w);
      *(ushort4*)&xb[i * 4] = o;
    }
  } else if (b < nxb + 96) {
    int idx = (b - nxb) * 256 + tid;
    int mat = idx >> 12;
    int off = (idx & 4095) * 4;
    float4 v = *(const float4*)&p.s[mat][off];
    ushort4 o;
    o.x = f2bf(v.x); o.y = f2bf(v.y); o.z = f2bf(v.z); o.w = f2bf(v.w);
    *(ushort4*)&p.d[mat][off] = o;
  } else {
    int e = (b - nxb - 96) * 256 + tid;
    if (e < E) atomicAdd(&hist[dst[e]], 1);
  }
}

// exclusive scan, 8 elements per thread, single block
__global__ __launch_bounds__(1024) void k_scan(const int* __restrict__ hist, int* __restrict__ offsets, int n) {
  __shared__ int wsum[16];
  int tid = threadIdx.x, lane = tid & 63, w = tid >> 6;
  int carry = 0;
  for (int base = 0; base < n; base += 8192) {
    int i0 = base + tid * 8;
    int v[8];
    #pragma unroll
    for (int j = 0; j < 8; ++j) { int i = i0 + j; v[j] = (i < n) ? hist[i] : 0; }
    int s = 0;
    #pragma unroll
    for (int j = 0; j < 8; ++j) { int t = v[j]; v[j] = s; s += t; }
    int x = s;
    #pragma unroll
    for (int off = 1; off < 64; off <<= 1) {
      int t = __shfl_up(x, off);
      if (lane >= off) x += t;
    }
    if (lane == 63) wsum[w] = x;
    __syncthreads();
    int wpre = 0, total = 0;
    #pragma unroll
    for (int k = 0; k < 16; ++k) { int t = wsum[k]; total += t; if (k < w) wpre += t; }
    int pre = carry + wpre + x - s;
    #pragma unroll
    for (int j = 0; j < 8; ++j) { int i = i0 + j; if (i < n) offsets[i] = pre + v[j]; }
    carry += total;
    __syncthreads();
  }
  if (tid == 0) offsets[n] = carry;
}

__global__ __launch_bounds__(256) void k_fill(const int* __restrict__ src, const int* __restrict__ dst,
                                              const int* __restrict__ offsets, int* __restrict__ cursor,
                                              int* __restrict__ ssrc, int E) {
  int e = blockIdx.x * 256 + threadIdx.x;
  if (e < E) {
    int d = dst[e];
    int pos = offsets[d] + atomicAdd(&cursor[d], 1);
    ssrc[pos] = src[e];
  }
}

// Fused layer: Out = relu(mean_agg(Xin) @ Wl^T + Xin @ Wr^T + b).
// Block = 64 nodes, 4 waves. Phase A: each wave aggregates 16 nodes (4x16-lane
// groups, 4x1KB gathers in flight) into LDS tile (stride 136 -> 2-way bank alias, free).
// Phase B: MFMA gemm, Agg-half of A read from LDS, Xin-half from global (L2-hot).
__global__ __launch_bounds__(256) void k_layer(const ushort* __restrict__ Xin,
                                               const int* __restrict__ offsets, const int* __restrict__ ssrc,
                                               const ushort* __restrict__ Wl, const ushort* __restrict__ Wr,
                                               const float* __restrict__ bias, ushort* __restrict__ Out, int n) {
  __shared__ ushort atile[64][136];
  int tid = threadIdx.x;
  int wave = tid >> 6, lane = tid & 63;
  int q = lane >> 4, r = lane & 15;
  int base = blockIdx.x * 64;

  // ---- phase A: aggregate ----
  for (int i = 0; i < 16; ++i) {
    int node = base + wave * 16 + i;
    float acc[8];
    #pragma unroll
    for (int t = 0; t < 8; ++t) acc[t] = 0.f;
    int deg = 0;
    if (node < n) {
      int o0 = offsets[node];
      deg = offsets[node + 1] - o0;
      for (int c0 = 0; c0 < deg; c0 += 64) {
        int cn = min(64, deg - c0);
        int myid = (lane < cn) ? ssrc[o0 + c0 + lane] : 0;
        for (int j = 0; j < cn; j += 16) {
          uint4 buf[4];
          #pragma unroll
          for (int t = 0; t < 4; ++t) {
            int e = j + t * 4 + q;
            buf[t] = (uint4){0u, 0u, 0u, 0u};
            if (e < cn) {
              int s = __shfl(myid, e);
              buf[t] = *(const uint4*)&Xin[(size_t)s * D + r * 8];
            }
          }
          #pragma unroll
          for (int t = 0; t < 4; ++t) {
            acc[0] += bf2f_lo(buf[t].x); acc[1] += bf2f_hi(buf[t].x);
            acc[2] += bf2f_lo(buf[t].y); acc[3] += bf2f_hi(buf[t].y);
            acc[4] += bf2f_lo(buf[t].z); acc[5] += bf2f_hi(buf[t].z);
            acc[6] += bf2f_lo(buf[t].w); acc[7] += bf2f_hi(buf[t].w);
          }
        }
      }
    }
    #pragma unroll
    for (int t = 0; t < 8; ++t) {
      acc[t] += __shfl_xor(acc[t], 16);
      acc[t] += __shfl_xor(acc[t], 32);
    }
    if (q == 0) {
      float inv = 1.f / (float)max(deg, 1);
      uint4 o;
      o.x = (unsigned)f2bf(acc[0] * inv) | ((unsigned)f2bf(acc[1] * inv) << 16);
      o.y = (unsigned)f2bf(acc[2] * inv) | ((unsigned)f2bf(acc[3] * inv) << 16);
      o.z = (unsigned)f2bf(acc[4] * inv) | ((unsigned)f2bf(acc[5] * inv) << 16);
      o.w = (unsigned)f2bf(acc[6] * inv) | ((unsigned)f2bf(acc[7] * inv) << 16);
      *(uint4*)&atile[wave * 16 + i][r * 8] = o;
    }
  }
  __syncthreads();

  // ---- phase B: gemm ----
  int wm = wave >> 1, wn = wave & 1;
  int m_base = base + wm * 32;
  int n_base = wn * 64;
  int kg = lane >> 4;

  f32x4 acc[2][4];
  #pragma unroll
  for (int i = 0; i < 2; ++i)
    #pragma unroll
    for (int j = 0; j < 4; ++j) acc[i][j] = (f32x4){0.f, 0.f, 0.f, 0.f};

  #pragma unroll
  for (int k0 = 0; k0 < 128; k0 += 32) {
    int kk = k0 + kg * 8;
    short8 a0[2], a1[2], b0[4], b1[4];
    #pragma unroll
    for (int fm = 0; fm < 2; ++fm) {
      a0[fm] = *(const short8*)&atile[wm * 32 + fm * 16 + r][kk];
      a1[fm] = *(const short8*)&Xin[(size_t)(m_base + fm * 16 + r) * D + kk];
    }
    #pragma unroll
    for (int fn = 0; fn < 4; ++fn) {
      b0[fn] = *(const short8*)&Wl[(size_t)(n_base + fn * 16 + r) * D + kk];
      b1[fn] = *(const short8*)&Wr[(size_t)(n_base + fn * 16 + r) * D + kk];
    }
    #pragma unroll
    for (int fm = 0; fm < 2; ++fm)
      #pragma unroll
      for (int fn = 0; fn < 4; ++fn) {
        acc[fm][fn] = __builtin_amdgcn_mfma_f32_16x16x32_bf16(a0[fm], b0[fn], acc[fm][fn], 0, 0, 0);
        acc[fm][fn] = __builtin_amdgcn_mfma_f32_16x16x32_bf16(a1[fm], b1[fn], acc[fm][fn], 0, 0, 0);
      }
  }
  #pragma unroll
  for (int fn = 0; fn < 4; ++fn) {
    int j = n_base + fn * 16 + r;
    float bj = bias[j];
    #pragma unroll
    for (int fm = 0; fm < 2; ++fm) {
      #pragma unroll
      for (int p = 0; p < 4; ++p) {
        int node = m_base + fm * 16 + kg * 4 + p;
        if (node < n) {
          float v = fmaxf(acc[fm][fn][p] + bj, 0.f);
          Out[(size_t)node * D + j] = f2bf(v);
        }
      }
    }
  }
}

__global__ __launch_bounds__(256) void k_pool_partial(const ushort* __restrict__ H, const int* __restrict__ batch,
                                                      float* __restrict__ partial, int n) {
  __shared__ float wsums[4][128];
  int g = blockIdx.x / PS, s = blockIdx.x % PS;
  int tid = threadIdx.x, wave = tid >> 6, lane = tid & 63;
  int a = 0, b = n;
  while (a < b) { int m = (a + b) >> 1; if (batch[m] < g) a = m + 1; else b = m; }
  int lo = a;
  b = n;
  while (a < b) { int m = (a + b) >> 1; if (batch[m] < g + 1) a = m + 1; else b = m; }
  int hi = a;
  int len = hi - lo;
  int chunk = (len + PS - 1) / PS;
  int a0 = lo + s * chunk;
  int a1 = min(a0 + chunk, hi);
  float ax = 0.f, ay = 0.f;
  for (int node = a0 + wave; node < a1; node += 4) {
    unsigned v = *(const unsigned*)&H[(size_t)node * D + lane * 2];
    ax += bf2f_lo(v);
    ay += bf2f_hi(v);
  }
  wsums[wave][lane * 2] = ax;
  wsums[wave][lane * 2 + 1] = ay;
  __syncthreads();
  if (tid < 128) {
    float v = wsums[0][tid] + wsums[1][tid] + wsums[2][tid] + wsums[3][tid];
    partial[(size_t)blockIdx.x * 128 + tid] = v;
  }
}

__global__ __launch_bounds__(256) void k_pool_fc2(const float* __restrict__ partial, const int* __restrict__ batch,
                                                  const float* __restrict__ Wfc, const float* __restrict__ bfc,
                                                  float* __restrict__ out, int n, int OUT) {
  __shared__ float pooled[128];
  int g = blockIdx.x;
  int tid = threadIdx.x, lane = tid & 63;
  int a = 0, b = n;
  while (a < b) { int m = (a + b) >> 1; if (batch[m] < g) a = m + 1; else b = m; }
  int lo = a;
  b = n;
  while (a < b) { int m = (a + b) >> 1; if (batch[m] < g + 1) a = m + 1; else b = m; }
  int hi = a;
  float inv = 1.f / (float)max(hi - lo, 1);
  if (tid < 128) {
    float v = 0.f;
    #pragma unroll
    for (int s = 0; s < PS; ++s) v += partial[(size_t)(g * PS + s) * 128 + tid];
    pooled[tid] = v * inv;
  }
  __syncthreads();
  if (tid < 64) {
    float2 p = *(const float2*)&pooled[lane * 2];
    for (int o = 0; o < OUT; ++o) {
      float2 w = *(const float2*)&Wfc[o * D + lane * 2];
      float part = p.x * w.x + p.y * w.y;
      #pragma unroll
      for (int off = 32; off > 0; off >>= 1) part += __shfl_down(part, off);
      if (lane == 0) out[g * OUT + o] = part + bfc[o];
    }
  }
}

extern "C" void kernel_launch(void* const* d_in, const int* in_sizes, int n_in,
                              void* d_out, int out_size, void* d_ws, size_t ws_size,
                              hipStream_t stream) {
  const float* x   = (const float*)d_in[0];
  const int* ei    = (const int*)d_in[1];
  const int* batch = (const int*)d_in[2];
  const float* W1l = (const float*)d_in[3];
  const float* W1r = (const float*)d_in[4];
  const float* b1  = (const float*)d_in[5];
  const float* W2l = (const float*)d_in[6];
  const float* W2r = (const float*)d_in[7];
  const float* b2  = (const float*)d_in[8];
  const float* W3l = (const float*)d_in[9];
  const float* W3r = (const float*)d_in[10];
  const float* b3  = (const float*)d_in[11];
  const float* Wfc = (const float*)d_in[12];
  const float* bfc = (const float*)d_in[13];
  float* out = (float*)d_out;

  int N = in_sizes[0] / D;
  int E = in_sizes[1] / 2;
  int OUT = in_sizes[12] / D;
  int G = out_size / OUT;
  const int* src = ei;
  const int* dst = ei + E;

  ushort* xb  = (ushort*)d_ws;
  ushort* h1  = xb + (size_t)N * D;
  ushort* h2  = h1 + (size_t)N * D;
  ushort* wb  = h2 + (size_t)N * D;
  int* ssrc   = (int*)(wb + 6 * 128 * 128);
  int* hist   = ssrc + E;
  int* cursor = hist + N;          // adjacent to hist: one memset covers both
  int* offsets = cursor + N;
  float* partial = (float*)(offsets + N + 2);   // G*PS*128 f32

  ushort* wl1 = wb + 0 * 16384; ushort* wr1 = wb + 1 * 16384;
  ushort* wl2 = wb + 2 * 16384; ushort* wr2 = wb + 3 * 16384;
  ushort* wl3 = wb + 4 * 16384; ushort* wr3 = wb + 5 * 16384;

  hipMemsetAsync(hist, 0, (size_t)2 * N * 4, stream);

  WPtrs wp;
  wp.s[0] = W1l; wp.s[1] = W1r; wp.s[2] = W2l; wp.s[3] = W2r; wp.s[4] = W3l; wp.s[5] = W3r;
  wp.d[0] = wl1; wp.d[1] = wr1; wp.d[2] = wl2; wp.d[3] = wr2; wp.d[4] = wl3; wp.d[5] = wr3;

  int n4 = N * D / 4;
  int nxb = (n4 + 255) / 256;
  int eb = (E + 255) / 256;
  k_prep<<<nxb + 96 + eb, 256, 0, stream>>>(x, xb, wp, dst, hist, n4, E);
  k_scan<<<1, 1024, 0, stream>>>(hist, offsets, N);
  k_fill<<<eb, 256, 0, stream>>>(src, dst, offsets, cursor, ssrc, E);

  int gb = (N + 63) / 64;
  k_layer<<<gb, 256, 0, stream>>>(xb, offsets, ssrc, wl1, wr1, b1, h1, N);
  k_layer<<<gb, 256, 0, stream>>>(h1, offsets, ssrc, wl2, wr2, b2, h2, N);
  k_layer<<<gb, 256, 0, stream>>>(h2, offsets, ssrc, wl3, wr3, b3, h1, N);

  k_pool_partial<<<G * PS, 256, 0, stream>>>(h1, batch, partial, N);
  k_pool_fc2<<<G, 256, 0, stream>>>(partial, batch, Wfc, bfc, out, N, OUT);
}

// Round 8
// 294.032 us; speedup vs baseline: 1.0928x; 1.0928x over previous
//
#include <hip/hip_runtime.h>

static constexpr int D = 128;
static constexpr int PS = 32;   // pool slices per graph

typedef __attribute__((ext_vector_type(8))) short short8;
typedef __attribute__((ext_vector_type(4))) float f32x4;

__device__ inline ushort f2bf(float f) {
  union { float f; unsigned u; } v; v.f = f;
  unsigned r = v.u + 0x7FFF + ((v.u >> 16) & 1);
  return (ushort)(r >> 16);
}
__device__ inline float bf2f_lo(unsigned p) {
  union { unsigned u; float f; } v; v.u = p << 16; return v.f;
}
__device__ inline float bf2f_hi(unsigned p) {
  union { unsigned u; float f; } v; v.u = p & 0xFFFF0000u; return v.f;
}

struct WPtrs { const float* s[6]; ushort* d[6]; };

// fused prep: [0,nxb) cvt x -> bf16 ; [nxb,nxb+96) cvt weights ; rest: dst histogram
__global__ __launch_bounds__(256) void k_prep(const float* __restrict__ x, ushort* __restrict__ xb, WPtrs p,
                                              const int* __restrict__ dst, int* __restrict__ hist,
                                              int n4x, int E) {
  int b = blockIdx.x, tid = threadIdx.x;
  int nxb = (n4x + 255) / 256;
  if (b < nxb) {
    int i = b * 256 + tid;
    if (i < n4x) {
      float4 v = *(const float4*)&x[i * 4];
      ushort4 o;
      o.x = f2bf(v.x); o.y = f2bf(v.y); o.z = f2bf(v.z); o.w = f2bf(v.w);
      *(ushort4*)&xb[i * 4] = o;
    }
  } else if (b < nxb + 96) {
    int idx = (b - nxb) * 256 + tid;
    int mat = idx >> 12;
    int off = (idx & 4095) * 4;
    float4 v = *(const float4*)&p.s[mat][off];
    ushort4 o;
    o.x = f2bf(v.x); o.y = f2bf(v.y); o.z = f2bf(v.z); o.w = f2bf(v.w);
    *(ushort4*)&p.d[mat][off] = o;
  } else {
    int e = (b - nxb - 96) * 256 + tid;
    if (e < E) atomicAdd(&hist[dst[e]], 1);
  }
}

// exclusive scan, 8 elements per thread, single block
__global__ __launch_bounds__(1024) void k_scan(const int* __restrict__ hist, int* __restrict__ offsets, int n) {
  __shared__ int wsum[16];
  int tid = threadIdx.x, lane = tid & 63, w = tid >> 6;
  int carry = 0;
  for (int base = 0; base < n; base += 8192) {
    int i0 = base + tid * 8;
    int v[8];
    #pragma unroll
    for (int j = 0; j < 8; ++j) { int i = i0 + j; v[j] = (i < n) ? hist[i] : 0; }
    int s = 0;
    #pragma unroll
    for (int j = 0; j < 8; ++j) { int t = v[j]; v[j] = s; s += t; }
    int x = s;
    #pragma unroll
    for (int off = 1; off < 64; off <<= 1) {
      int t = __shfl_up(x, off);
      if (lane >= off) x += t;
    }
    if (lane == 63) wsum[w] = x;
    __syncthreads();
    int wpre = 0, total = 0;
    #pragma unroll
    for (int k = 0; k < 16; ++k) { int t = wsum[k]; total += t; if (k < w) wpre += t; }
    int pre = carry + wpre + x - s;
    #pragma unroll
    for (int j = 0; j < 8; ++j) { int i = i0 + j; if (i < n) offsets[i] = pre + v[j]; }
    carry += total;
    __syncthreads();
  }
  if (tid == 0) offsets[n] = carry;
}

__global__ __launch_bounds__(256) void k_fill(const int* __restrict__ src, const int* __restrict__ dst,
                                              const int* __restrict__ offsets, int* __restrict__ cursor,
                                              int* __restrict__ ssrc, int E) {
  int e = blockIdx.x * 256 + threadIdx.x;
  if (e < E) {
    int d = dst[e];
    int pos = offsets[d] + atomicAdd(&cursor[d], 1);
    ssrc[pos] = src[e];
  }
}

// 2 nodes per wave; 4 x 16-lane groups; 8 x 1KB gathers in flight (4 per node).
__global__ __launch_bounds__(256) void k_aggregate_bf(const ushort* __restrict__ X, const int* __restrict__ offsets,
                                                      const int* __restrict__ ssrc, ushort* __restrict__ Agg, int n) {
  int wpair = (blockIdx.x * 256 + threadIdx.x) >> 6;
  int lane = threadIdx.x & 63;
  int nA = wpair * 2, nB = nA + 1;
  if (nA >= n) return;
  int q = lane >> 4, r = lane & 15;

  int oA0 = offsets[nA], degA = offsets[nA + 1] - oA0;
  int oB0 = 0, degB = 0;
  if (nB < n) { oB0 = offsets[nB]; degB = offsets[nB + 1] - oB0; }

  float accA[8], accB[8];
  #pragma unroll
  for (int i = 0; i < 8; ++i) { accA[i] = 0.f; accB[i] = 0.f; }

  int dmax = max(degA, degB);
  for (int c0 = 0; c0 < dmax; c0 += 64) {
    int cnA = min(64, degA - c0);
    int cnB = min(64, degB - c0);
    int idA = (lane < cnA) ? ssrc[oA0 + c0 + lane] : 0;
    int idB = (lane < cnB) ? ssrc[oB0 + c0 + lane] : 0;
    int cmax = max(cnA, cnB);
    for (int j = 0; j < cmax; j += 16) {
      uint4 bufA[4], bufB[4];
      #pragma unroll
      for (int t = 0; t < 4; ++t) {
        int e = j + t * 4 + q;
        bufA[t] = (uint4){0u, 0u, 0u, 0u};
        if (e < cnA) {
          int s = __shfl(idA, e);
          bufA[t] = *(const uint4*)&X[(size_t)s * D + r * 8];
        }
      }
      #pragma unroll
      for (int t = 0; t < 4; ++t) {
        int e = j + t * 4 + q;
        bufB[t] = (uint4){0u, 0u, 0u, 0u};
        if (e < cnB) {
          int s = __shfl(idB, e);
          bufB[t] = *(const uint4*)&X[(size_t)s * D + r * 8];
        }
      }
      #pragma unroll
      for (int t = 0; t < 4; ++t) {
        accA[0] += bf2f_lo(bufA[t].x); accA[1] += bf2f_hi(bufA[t].x);
        accA[2] += bf2f_lo(bufA[t].y); accA[3] += bf2f_hi(bufA[t].y);
        accA[4] += bf2f_lo(bufA[t].z); accA[5] += bf2f_hi(bufA[t].z);
        accA[6] += bf2f_lo(bufA[t].w); accA[7] += bf2f_hi(bufA[t].w);
        accB[0] += bf2f_lo(bufB[t].x); accB[1] += bf2f_hi(bufB[t].x);
        accB[2] += bf2f_lo(bufB[t].y); accB[3] += bf2f_hi(bufB[t].y);
        accB[4] += bf2f_lo(bufB[t].z); accB[5] += bf2f_hi(bufB[t].z);
        accB[6] += bf2f_lo(bufB[t].w); accB[7] += bf2f_hi(bufB[t].w);
      }
    }
  }
  #pragma unroll
  for (int i = 0; i < 8; ++i) {
    accA[i] += __shfl_xor(accA[i], 16);
    accA[i] += __shfl_xor(accA[i], 32);
    accB[i] += __shfl_xor(accB[i], 16);
    accB[i] += __shfl_xor(accB[i], 32);
  }
  if (q == 0) {
    float inv = 1.f / (float)max(degA, 1);
    uint4 o;
    o.x = (unsigned)f2bf(accA[0] * inv) | ((unsigned)f2bf(accA[1] * inv) << 16);
    o.y = (unsigned)f2bf(accA[2] * inv) | ((unsigned)f2bf(accA[3] * inv) << 16);
    o.z = (unsigned)f2bf(accA[4] * inv) | ((unsigned)f2bf(accA[5] * inv) << 16);
    o.w = (unsigned)f2bf(accA[6] * inv) | ((unsigned)f2bf(accA[7] * inv) << 16);
    *(uint4*)&Agg[(size_t)nA * D + r * 8] = o;
  } else if (q == 1 && nB < n) {
    float inv = 1.f / (float)max(degB, 1);
    uint4 o;
    o.x = (unsigned)f2bf(accB[0] * inv) | ((unsigned)f2bf(accB[1] * inv) << 16);
    o.y = (unsigned)f2bf(accB[2] * inv) | ((unsigned)f2bf(accB[3] * inv) << 16);
    o.z = (unsigned)f2bf(accB[4] * inv) | ((unsigned)f2bf(accB[5] * inv) << 16);
    o.w = (unsigned)f2bf(accB[6] * inv) | ((unsigned)f2bf(accB[7] * inv) << 16);
    *(uint4*)&Agg[(size_t)nB * D + r * 8] = o;
  }
}

// Out = relu(Agg @ Wl^T + Xin @ Wr^T + b). N-split: block = 64 nodes x 64 outs,
// wave = 32 nodes x 32 outs. 2x blocks vs full-N for latency hiding.
__global__ __launch_bounds__(256) void k_gemm_mfma(const ushort* __restrict__ Abf, const ushort* __restrict__ Xbf,
                                                   const ushort* __restrict__ Wl, const ushort* __restrict__ Wr,
                                                   const float* __restrict__ bias, ushort* __restrict__ Out, int n) {
  int tid = threadIdx.x;
  int wave = tid >> 6, lane = tid & 63;
  int mb = blockIdx.x >> 1, nh = blockIdx.x & 1;
  int wm = wave >> 1, wn = wave & 1;
  int m_base = mb * 64 + wm * 32;
  int n_base = nh * 64 + wn * 32;
  int r = lane & 15, kg = lane >> 4;

  f32x4 acc[2][2];
  #pragma unroll
  for (int i = 0; i < 2; ++i)
    #pragma unroll
    for (int j = 0; j < 2; ++j) acc[i][j] = (f32x4){0.f, 0.f, 0.f, 0.f};

  const ushort* As[2] = {Abf, Xbf};
  const ushort* Ws[2] = {Wl, Wr};
  #pragma unroll
  for (int half = 0; half < 2; ++half) {
    const ushort* A = As[half];
    const ushort* W = Ws[half];
    #pragma unroll
    for (int k0 = 0; k0 < 128; k0 += 32) {
      int kk = k0 + kg * 8;
      short8 a[2], b[2];
      #pragma unroll
      for (int fm = 0; fm < 2; ++fm)
        a[fm] = *(const short8*)&A[(size_t)(m_base + fm * 16 + r) * D + kk];
      #pragma unroll
      for (int fn = 0; fn < 2; ++fn)
        b[fn] = *(const short8*)&W[(size_t)(n_base + fn * 16 + r) * D + kk];
      #pragma unroll
      for (int fm = 0; fm < 2; ++fm)
        #pragma unroll
        for (int fn = 0; fn < 2; ++fn)
          acc[fm][fn] = __builtin_amdgcn_mfma_f32_16x16x32_bf16(a[fm], b[fn], acc[fm][fn], 0, 0, 0);
    }
  }
  #pragma unroll
  for (int fn = 0; fn < 2; ++fn) {
    int j = n_base + fn * 16 + r;
    float bj = bias[j];
    #pragma unroll
    for (int fm = 0; fm < 2; ++fm) {
      #pragma unroll
      for (int p = 0; p < 4; ++p) {
        int node = m_base + fm * 16 + kg * 4 + p;
        float v = fmaxf(acc[fm][fn][p] + bj, 0.f);
        Out[(size_t)node * D + j] = f2bf(v);
      }
    }
  }
}

__global__ __launch_bounds__(256) void k_pool_partial(const ushort* __restrict__ H, const int* __restrict__ batch,
                                                      float* __restrict__ partial, int n) {
  __shared__ float wsums[4][128];
  int g = blockIdx.x / PS, s = blockIdx.x % PS;
  int tid = threadIdx.x, wave = tid >> 6, lane = tid & 63;
  int a = 0, b = n;
  while (a < b) { int m = (a + b) >> 1; if (batch[m] < g) a = m + 1; else b = m; }
  int lo = a;
  b = n;
  while (a < b) { int m = (a + b) >> 1; if (batch[m] < g + 1) a = m + 1; else b = m; }
  int hi = a;
  int len = hi - lo;
  int chunk = (len + PS - 1) / PS;
  int a0 = lo + s * chunk;
  int a1 = min(a0 + chunk, hi);
  float ax = 0.f, ay = 0.f;
  for (int node = a0 + wave; node < a1; node += 4) {
    unsigned v = *(const unsigned*)&H[(size_t)node * D + lane * 2];
    ax += bf2f_lo(v);
    ay += bf2f_hi(v);
  }
  wsums[wave][lane * 2] = ax;
  wsums[wave][lane * 2 + 1] = ay;
  __syncthreads();
  if (tid < 128) {
    float v = wsums[0][tid] + wsums[1][tid] + wsums[2][tid] + wsums[3][tid];
    partial[(size_t)blockIdx.x * 128 + tid] = v;
  }
}

__global__ __launch_bounds__(256) void k_pool_fc2(const float* __restrict__ partial, const int* __restrict__ batch,
                                                  const float* __restrict__ Wfc, const float* __restrict__ bfc,
                                                  float* __restrict__ out, int n, int OUT) {
  __shared__ float pooled[128];
  int g = blockIdx.x;
  int tid = threadIdx.x, lane = tid & 63;
  int a = 0, b = n;
  while (a < b) { int m = (a + b) >> 1; if (batch[m] < g) a = m + 1; else b = m; }
  int lo = a;
  b = n;
  while (a < b) { int m = (a + b) >> 1; if (batch[m] < g + 1) a = m + 1; else b = m; }
  int hi = a;
  float inv = 1.f / (float)max(hi - lo, 1);
  if (tid < 128) {
    float v = 0.f;
    #pragma unroll
    for (int s = 0; s < PS; ++s) v += partial[(size_t)(g * PS + s) * 128 + tid];
    pooled[tid] = v * inv;
  }
  __syncthreads();
  if (tid < 64) {
    float2 p = *(const float2*)&pooled[lane * 2];
    for (int o = 0; o < OUT; ++o) {
      float2 w = *(const float2*)&Wfc[o * D + lane * 2];
      float part = p.x * w.x + p.y * w.y;
      #pragma unroll
      for (int off = 32; off > 0; off >>= 1) part += __shfl_down(part, off);
      if (lane == 0) out[g * OUT + o] = part + bfc[o];
    }
  }
}

extern "C" void kernel_launch(void* const* d_in, const int* in_sizes, int n_in,
                              void* d_out, int out_size, void* d_ws, size_t ws_size,
                              hipStream_t stream) {
  const float* x   = (const float*)d_in[0];
  const int* ei    = (const int*)d_in[1];
  const int* batch = (const int*)d_in[2];
  const float* W1l = (const float*)d_in[3];
  const float* W1r = (const float*)d_in[4];
  const float* b1  = (const float*)d_in[5];
  const float* W2l = (const float*)d_in[6];
  const float* W2r = (const float*)d_in[7];
  const float* b2  = (const float*)d_in[8];
  const float* W3l = (const float*)d_in[9];
  const float* W3r = (const float*)d_in[10];
  const float* b3  = (const float*)d_in[11];
  const float* Wfc = (const float*)d_in[12];
  const float* bfc = (const float*)d_in[13];
  float* out = (float*)d_out;

  int N = in_sizes[0] / D;
  int E = in_sizes[1] / 2;
  int OUT = in_sizes[12] / D;
  int G = out_size / OUT;
  const int* src = ei;
  const int* dst = ei + E;

  ushort* xb  = (ushort*)d_ws;
  ushort* agg = xb + (size_t)N * D;
  ushort* h1  = agg + (size_t)N * D;
  ushort* h2  = h1 + (size_t)N * D;
  ushort* wb  = h2 + (size_t)N * D;
  int* ssrc   = (int*)(wb + 6 * 128 * 128);
  int* hist   = ssrc + E;
  int* cursor = hist + N;
  int* offsets = cursor + N;
  float* partial = (float*)(offsets + N + 2);

  ushort* wl1 = wb + 0 * 16384; ushort* wr1 = wb + 1 * 16384;
  ushort* wl2 = wb + 2 * 16384; ushort* wr2 = wb + 3 * 16384;
  ushort* wl3 = wb + 4 * 16384; ushort* wr3 = wb + 5 * 16384;

  hipMemsetAsync(hist, 0, (size_t)2 * N * 4, stream);

  WPtrs wp;
  wp.s[0] = W1l; wp.s[1] = W1r; wp.s[2] = W2l; wp.s[3] = W2r; wp.s[4] = W3l; wp.s[5] = W3r;
  wp.d[0] = wl1; wp.d[1] = wr1; wp.d[2] = wl2; wp.d[3] = wr2; wp.d[4] = wl3; wp.d[5] = wr3;

  int n4 = N * D / 4;
  int nxb = (n4 + 255) / 256;
  int eb = (E + 255) / 256;
  k_prep<<<nxb + 96 + eb, 256, 0, stream>>>(x, xb, wp, dst, hist, n4, E);
  k_scan<<<1, 1024, 0, stream>>>(hist, offsets, N);
  k_fill<<<eb, 256, 0, stream>>>(src, dst, offsets, cursor, ssrc, E);

  int ab = (((N + 1) / 2) * 64 + 255) / 256;
  int gb = ((N + 63) / 64) * 2;

  k_aggregate_bf<<<ab, 256, 0, stream>>>(xb, offsets, ssrc, agg, N);
  k_gemm_mfma<<<gb, 256, 0, stream>>>(agg, xb, wl1, wr1, b1, h1, N);

  k_aggregate_bf<<<ab, 256, 0, stream>>>(h1, offsets, ssrc, agg, N);
  k_gemm_mfma<<<gb, 256, 0, stream>>>(agg, h1, wl2, wr2, b2, h2, N);

  k_aggregate_bf<<<ab, 256, 0, stream>>>(h2, offsets, ssrc, agg, N);
  k_gemm_mfma<<<gb, 256, 0, stream>>>(agg, h2, wl3, wr3, b3, h1, N);

  k_pool_partial<<<G * PS, 256, 0, stream>>>(h1, batch, partial, N);
  k_pool_fc2<<<G, 256, 0, stream>>>(partial, batch, Wfc, bfc, out, N, OUT);
}

// Round 9
// 270.951 us; speedup vs baseline: 1.1859x; 1.0852x over previous
//
#include <hip/hip_runtime.h>

static constexpr int D = 128;
static constexpr int PS = 32;   // pool slices per graph

typedef __attribute__((ext_vector_type(8))) short short8;
typedef __attribute__((ext_vector_type(4))) float f32x4;

__device__ inline ushort f2bf(float f) {
  union { float f; unsigned u; } v; v.f = f;
  unsigned r = v.u + 0x7FFF + ((v.u >> 16) & 1);
  return (ushort)(r >> 16);
}
__device__ inline float bf2f_lo(unsigned p) {
  union { unsigned u; float f; } v; v.u = p << 16; return v.f;
}
__device__ inline float bf2f_hi(unsigned p) {
  union { unsigned u; float f; } v; v.u = p & 0xFFFF0000u; return v.f;
}

struct WPtrs { const float* s[6]; ushort* d[6]; };

// fused prep: [0,nxb) cvt x -> bf16 ; [nxb,nxb+96) cvt weights ; rest: dst histogram
__global__ __launch_bounds__(256) void k_prep(const float* __restrict__ x, ushort* __restrict__ xb, WPtrs p,
                                              const int* __restrict__ dst, int* __restrict__ hist,
                                              int n4x, int E) {
  int b = blockIdx.x, tid = threadIdx.x;
  int nxb = (n4x + 255) / 256;
  if (b < nxb) {
    int i = b * 256 + tid;
    if (i < n4x) {
      float4 v = *(const float4*)&x[i * 4];
      ushort4 o;
      o.x = f2bf(v.x); o.y = f2bf(v.y); o.z = f2bf(v.z); o.w = f2bf(v.w);
      *(ushort4*)&xb[i * 4] = o;
    }
  } else if (b < nxb + 96) {
    int idx = (b - nxb) * 256 + tid;
    int mat = idx >> 12;
    int off = (idx & 4095) * 4;
    float4 v = *(const float4*)&p.s[mat][off];
    ushort4 o;
    o.x = f2bf(v.x); o.y = f2bf(v.y); o.z = f2bf(v.z); o.w = f2bf(v.w);
    *(ushort4*)&p.d[mat][off] = o;
  } else {
    int e = (b - nxb - 96) * 256 + tid;
    if (e < E) atomicAdd(&hist[dst[e]], 1);
  }
}

// exclusive scan, 8 elements per thread, single block
__global__ __launch_bounds__(1024) void k_scan(const int* __restrict__ hist, int* __restrict__ offsets, int n) {
  __shared__ int wsum[16];
  int tid = threadIdx.x, lane = tid & 63, w = tid >> 6;
  int carry = 0;
  for (int base = 0; base < n; base += 8192) {
    int i0 = base + tid * 8;
    int v[8];
    #pragma unroll
    for (int j = 0; j < 8; ++j) { int i = i0 + j; v[j] = (i < n) ? hist[i] : 0; }
    int s = 0;
    #pragma unroll
    for (int j = 0; j < 8; ++j) { int t = v[j]; v[j] = s; s += t; }
    int x = s;
    #pragma unroll
    for (int off = 1; off < 64; off <<= 1) {
      int t = __shfl_up(x, off);
      if (lane >= off) x += t;
    }
    if (lane == 63) wsum[w] = x;
    __syncthreads();
    int wpre = 0, total = 0;
    #pragma unroll
    for (int k = 0; k < 16; ++k) { int t = wsum[k]; total += t; if (k < w) wpre += t; }
    int pre = carry + wpre + x - s;
    #pragma unroll
    for (int j = 0; j < 8; ++j) { int i = i0 + j; if (i < n) offsets[i] = pre + v[j]; }
    carry += total;
    __syncthreads();
  }
  if (tid == 0) offsets[n] = carry;
}

__global__ __launch_bounds__(256) void k_fill(const int* __restrict__ src, const int* __restrict__ dst,
                                              const int* __restrict__ offsets, int* __restrict__ cursor,
                                              int* __restrict__ ssrc, int E) {
  int e = blockIdx.x * 256 + threadIdx.x;
  if (e < E) {
    int d = dst[e];
    int pos = offsets[d] + atomicAdd(&cursor[d], 1);
    ssrc[pos] = src[e];
  }
}

// one wave per node; 4 x 16-lane groups, 16 edges (4 x 1KB gathers) in flight per iter;
// edge ids for up to 64 edges preloaded in one register, distributed via shfl. (R6 version)
__global__ __launch_bounds__(256) void k_aggregate_bf(const ushort* __restrict__ X, const int* __restrict__ offsets,
                                                      const int* __restrict__ ssrc, ushort* __restrict__ Agg, int n) {
  int wid = (blockIdx.x * 256 + threadIdx.x) >> 6;
  int lane = threadIdx.x & 63;
  if (wid >= n) return;
  int q = lane >> 4, r = lane & 15;
  int o0 = offsets[wid], deg = offsets[wid + 1] - o0;

  float acc[8];
  #pragma unroll
  for (int i = 0; i < 8; ++i) acc[i] = 0.f;

  for (int c0 = 0; c0 < deg; c0 += 64) {
    int cn = min(64, deg - c0);
    int myid = (lane < cn) ? ssrc[o0 + c0 + lane] : 0;
    for (int j = 0; j < cn; j += 16) {
      uint4 buf[4];
      #pragma unroll
      for (int t = 0; t < 4; ++t) {
        int e = j + t * 4 + q;
        buf[t] = (uint4){0u, 0u, 0u, 0u};
        if (e < cn) {
          int s = __shfl(myid, e);
          buf[t] = *(const uint4*)&X[(size_t)s * D + r * 8];
        }
      }
      #pragma unroll
      for (int t = 0; t < 4; ++t) {
        acc[0] += bf2f_lo(buf[t].x); acc[1] += bf2f_hi(buf[t].x);
        acc[2] += bf2f_lo(buf[t].y); acc[3] += bf2f_hi(buf[t].y);
        acc[4] += bf2f_lo(buf[t].z); acc[5] += bf2f_hi(buf[t].z);
        acc[6] += bf2f_lo(buf[t].w); acc[7] += bf2f_hi(buf[t].w);
      }
    }
  }
  #pragma unroll
  for (int i = 0; i < 8; ++i) {
    acc[i] += __shfl_xor(acc[i], 16);
    acc[i] += __shfl_xor(acc[i], 32);
  }
  if (q == 0) {
    float inv = 1.f / (float)max(deg, 1);
    uint4 o;
    o.x = (unsigned)f2bf(acc[0] * inv) | ((unsigned)f2bf(acc[1] * inv) << 16);
    o.y = (unsigned)f2bf(acc[2] * inv) | ((unsigned)f2bf(acc[3] * inv) << 16);
    o.z = (unsigned)f2bf(acc[4] * inv) | ((unsigned)f2bf(acc[5] * inv) << 16);
    o.w = (unsigned)f2bf(acc[6] * inv) | ((unsigned)f2bf(acc[7] * inv) << 16);
    *(uint4*)&Agg[(size_t)wid * D + r * 8] = o;
  }
}

// Out = relu(Agg @ Wl^T + Xin @ Wr^T + b). M-split: block = 32 nodes x 128 outs
// (grid 1250 for latency hiding), wave = 32 nodes x 32 outs, acc 2x2 frags.
__global__ __launch_bounds__(256) void k_gemm_mfma(const ushort* __restrict__ Abf, const ushort* __restrict__ Xbf,
                                                   const ushort* __restrict__ Wl, const ushort* __restrict__ Wr,
                                                   const float* __restrict__ bias, ushort* __restrict__ Out, int n) {
  int tid = threadIdx.x;
  int wave = tid >> 6, lane = tid & 63;
  int m_base = blockIdx.x * 32;
  int n_base = wave * 32;
  int r = lane & 15, kg = lane >> 4;

  f32x4 acc[2][2];
  #pragma unroll
  for (int i = 0; i < 2; ++i)
    #pragma unroll
    for (int j = 0; j < 2; ++j) acc[i][j] = (f32x4){0.f, 0.f, 0.f, 0.f};

  const ushort* As[2] = {Abf, Xbf};
  const ushort* Ws[2] = {Wl, Wr};
  #pragma unroll
  for (int half = 0; half < 2; ++half) {
    const ushort* A = As[half];
    const ushort* W = Ws[half];
    #pragma unroll
    for (int k0 = 0; k0 < 128; k0 += 32) {
      int kk = k0 + kg * 8;
      short8 a[2], b[2];
      #pragma unroll
      for (int fm = 0; fm < 2; ++fm)
        a[fm] = *(const short8*)&A[(size_t)(m_base + fm * 16 + r) * D + kk];
      #pragma unroll
      for (int fn = 0; fn < 2; ++fn)
        b[fn] = *(const short8*)&W[(size_t)(n_base + fn * 16 + r) * D + kk];
      #pragma unroll
      for (int fm = 0; fm < 2; ++fm)
        #pragma unroll
        for (int fn = 0; fn < 2; ++fn)
          acc[fm][fn] = __builtin_amdgcn_mfma_f32_16x16x32_bf16(a[fm], b[fn], acc[fm][fn], 0, 0, 0);
    }
  }
  #pragma unroll
  for (int fn = 0; fn < 2; ++fn) {
    int j = n_base + fn * 16 + r;
    float bj = bias[j];
    #pragma unroll
    for (int fm = 0; fm < 2; ++fm) {
      #pragma unroll
      for (int p = 0; p < 4; ++p) {
        int node = m_base + fm * 16 + kg * 4 + p;
        if (node < n) {
          float v = fmaxf(acc[fm][fn][p] + bj, 0.f);
          Out[(size_t)node * D + j] = f2bf(v);
        }
      }
    }
  }
}

__global__ __launch_bounds__(256) void k_pool_partial(const ushort* __restrict__ H, const int* __restrict__ batch,
                                                      float* __restrict__ partial, int n) {
  __shared__ float wsums[4][128];
  int g = blockIdx.x / PS, s = blockIdx.x % PS;
  int tid = threadIdx.x, wave = tid >> 6, lane = tid & 63;
  int a = 0, b = n;
  while (a < b) { int m = (a + b) >> 1; if (batch[m] < g) a = m + 1; else b = m; }
  int lo = a;
  b = n;
  while (a < b) { int m = (a + b) >> 1; if (batch[m] < g + 1) a = m + 1; else b = m; }
  int hi = a;
  int len = hi - lo;
  int chunk = (len + PS - 1) / PS;
  int a0 = lo + s * chunk;
  int a1 = min(a0 + chunk, hi);
  float ax = 0.f, ay = 0.f;
  for (int node = a0 + wave; node < a1; node += 4) {
    unsigned v = *(const unsigned*)&H[(size_t)node * D + lane * 2];
    ax += bf2f_lo(v);
    ay += bf2f_hi(v);
  }
  wsums[wave][lane * 2] = ax;
  wsums[wave][lane * 2 + 1] = ay;
  __syncthreads();
  if (tid < 128) {
    float v = wsums[0][tid] + wsums[1][tid] + wsums[2][tid] + wsums[3][tid];
    partial[(size_t)blockIdx.x * 128 + tid] = v;
  }
}

__global__ __launch_bounds__(256) void k_pool_fc2(const float* __restrict__ partial, const int* __restrict__ batch,
                                                  const float* __restrict__ Wfc, const float* __restrict__ bfc,
                                                  float* __restrict__ out, int n, int OUT) {
  __shared__ float pooled[128];
  int g = blockIdx.x;
  int tid = threadIdx.x, lane = tid & 63;
  int a = 0, b = n;
  while (a < b) { int m = (a + b) >> 1; if (batch[m] < g) a = m + 1; else b = m; }
  int lo = a;
  b = n;
  while (a < b) { int m = (a + b) >> 1; if (batch[m] < g + 1) a = m + 1; else b = m; }
  int hi = a;
  float inv = 1.f / (float)max(hi - lo, 1);
  if (tid < 128) {
    float v = 0.f;
    #pragma unroll
    for (int s = 0; s < PS; ++s) v += partial[(size_t)(g * PS + s) * 128 + tid];
    pooled[tid] = v * inv;
  }
  __syncthreads();
  if (tid < 64) {
    float2 p = *(const float2*)&pooled[lane * 2];
    for (int o = 0; o < OUT; ++o) {
      float2 w = *(const float2*)&Wfc[o * D + lane * 2];
      float part = p.x * w.x + p.y * w.y;
      #pragma unroll
      for (int off = 32; off > 0; off >>= 1) part += __shfl_down(part, off);
      if (lane == 0) out[g * OUT + o] = part + bfc[o];
    }
  }
}

extern "C" void kernel_launch(void* const* d_in, const int* in_sizes, int n_in,
                              void* d_out, int out_size, void* d_ws, size_t ws_size,
                              hipStream_t stream) {
  const float* x   = (const float*)d_in[0];
  const int* ei    = (const int*)d_in[1];
  const int* batch = (const int*)d_in[2];
  const float* W1l = (const float*)d_in[3];
  const float* W1r = (const float*)d_in[4];
  const float* b1  = (const float*)d_in[5];
  const float* W2l = (const float*)d_in[6];
  const float* W2r = (const float*)d_in[7];
  const float* b2  = (const float*)d_in[8];
  const float* W3l = (const float*)d_in[9];
  const float* W3r = (const float*)d_in[10];
  const float* b3  = (const float*)d_in[11];
  const float* Wfc = (const float*)d_in[12];
  const float* bfc = (const float*)d_in[13];
  float* out = (float*)d_out;

  int N = in_sizes[0] / D;
  int E = in_sizes[1] / 2;
  int OUT = in_sizes[12] / D;
  int G = out_size / OUT;
  const int* src = ei;
  const int* dst = ei + E;

  ushort* xb  = (ushort*)d_ws;
  ushort* agg = xb + (size_t)N * D;
  ushort* h1  = agg + (size_t)N * D;
  ushort* h2  = h1 + (size_t)N * D;
  ushort* wb  = h2 + (size_t)N * D;
  int* ssrc   = (int*)(wb + 6 * 128 * 128);
  int* hist   = ssrc + E;
  int* cursor = hist + N;
  int* offsets = cursor + N;
  float* partial = (float*)(offsets + N + 2);

  ushort* wl1 = wb + 0 * 16384; ushort* wr1 = wb + 1 * 16384;
  ushort* wl2 = wb + 2 * 16384; ushort* wr2 = wb + 3 * 16384;
  ushort* wl3 = wb + 4 * 16384; ushort* wr3 = wb + 5 * 16384;

  hipMemsetAsync(hist, 0, (size_t)2 * N * 4, stream);

  WPtrs wp;
  wp.s[0] = W1l; wp.s[1] = W1r; wp.s[2] = W2l; wp.s[3] = W2r; wp.s[4] = W3l; wp.s[5] = W3r;
  wp.d[0] = wl1; wp.d[1] = wr1; wp.d[2] = wl2; wp.d[3] = wr2; wp.d[4] = wl3; wp.d[5] = wr3;

  int n4 = N * D / 4;
  int nxb = (n4 + 255) / 256;
  int eb = (E + 255) / 256;
  k_prep<<<nxb + 96 + eb, 256, 0, stream>>>(x, xb, wp, dst, hist, n4, E);
  k_scan<<<1, 1024, 0, stream>>>(hist, offsets, N);
  k_fill<<<eb, 256, 0, stream>>>(src, dst, offsets, cursor, ssrc, E);

  int ab = (N * 64 + 255) / 256;
  int gb = (N + 31) / 32;

  k_aggregate_bf<<<ab, 256, 0, stream>>>(xb, offsets, ssrc, agg, N);
  k_gemm_mfma<<<gb, 256, 0, stream>>>(agg, xb, wl1, wr1, b1, h1, N);

  k_aggregate_bf<<<ab, 256, 0, stream>>>(h1, offsets, ssrc, agg, N);
  k_gemm_mfma<<<gb, 256, 0, stream>>>(agg, h1, wl2, wr2, b2, h2, N);

  k_aggregate_bf<<<ab, 256, 0, stream>>>(h2, offsets, ssrc, agg, N);
  k_gemm_mfma<<<gb, 256, 0, stream>>>(agg, h2, wl3, wr3, b3, h1, N);

  k_pool_partial<<<G * PS, 256, 0, stream>>>(h1, batch, partial, N);
  k_pool_fc2<<<G, 256, 0, stream>>>(partial, batch, Wfc, bfc, out, N, OUT);
}

// Round 10
// 263.408 us; speedup vs baseline: 1.2199x; 1.0286x over previous
//
#include <hip/hip_runtime.h>

static constexpr int D = 128;
static constexpr int PS = 32;   // pool slices per graph

typedef __attribute__((ext_vector_type(8))) short short8;
typedef __attribute__((ext_vector_type(4))) float f32x4;

__device__ inline ushort f2bf(float f) {
  union { float f; unsigned u; } v; v.f = f;
  unsigned r = v.u + 0x7FFF + ((v.u >> 16) & 1);
  return (ushort)(r >> 16);
}
__device__ inline float bf2f_lo(unsigned p) {
  union { unsigned u; float f; } v; v.u = p << 16; return v.f;
}
__device__ inline float bf2f_hi(unsigned p) {
  union { unsigned u; float f; } v; v.u = p & 0xFFFF0000u; return v.f;
}

struct WPtrs { const float* s[6]; ushort* d[6]; };

// zero hist+cursor (n16 uint4 elements) — replaces 41us rocclr fill
__global__ __launch_bounds__(256) void k_zero(uint4* __restrict__ p, int n16) {
  int i = blockIdx.x * 256 + threadIdx.x;
  if (i < n16) p[i] = (uint4){0u, 0u, 0u, 0u};
}

// fused prep: [0,nxb) cvt x -> bf16 ; [nxb,nxb+96) cvt weights ; rest: dst histogram
__global__ __launch_bounds__(256) void k_prep(const float* __restrict__ x, ushort* __restrict__ xb, WPtrs p,
                                              const int* __restrict__ dst, int* __restrict__ hist,
                                              int n4x, int E) {
  int b = blockIdx.x, tid = threadIdx.x;
  int nxb = (n4x + 255) / 256;
  if (b < nxb) {
    int i = b * 256 + tid;
    if (i < n4x) {
      float4 v = *(const float4*)&x[i * 4];
      ushort4 o;
      o.x = f2bf(v.x); o.y = f2bf(v.y); o.z = f2bf(v.z); o.w = f2bf(v.w);
      *(ushort4*)&xb[i * 4] = o;
    }
  } else if (b < nxb + 96) {
    int idx = (b - nxb) * 256 + tid;
    int mat = idx >> 12;
    int off = (idx & 4095) * 4;
    float4 v = *(const float4*)&p.s[mat][off];
    ushort4 o;
    o.x = f2bf(v.x); o.y = f2bf(v.y); o.z = f2bf(v.z); o.w = f2bf(v.w);
    *(ushort4*)&p.d[mat][off] = o;
  } else {
    int e = (b - nxb - 96) * 256 + tid;
    if (e < E) atomicAdd(&hist[dst[e]], 1);
  }
}

// exclusive scan, 8 elements per thread, single block
__global__ __launch_bounds__(1024) void k_scan(const int* __restrict__ hist, int* __restrict__ offsets, int n) {
  __shared__ int wsum[16];
  int tid = threadIdx.x, lane = tid & 63, w = tid >> 6;
  int carry = 0;
  for (int base = 0; base < n; base += 8192) {
    int i0 = base + tid * 8;
    int v[8];
    #pragma unroll
    for (int j = 0; j < 8; ++j) { int i = i0 + j; v[j] = (i < n) ? hist[i] : 0; }
    int s = 0;
    #pragma unroll
    for (int j = 0; j < 8; ++j) { int t = v[j]; v[j] = s; s += t; }
    int x = s;
    #pragma unroll
    for (int off = 1; off < 64; off <<= 1) {
      int t = __shfl_up(x, off);
      if (lane >= off) x += t;
    }
    if (lane == 63) wsum[w] = x;
    __syncthreads();
    int wpre = 0, total = 0;
    #pragma unroll
    for (int k = 0; k < 16; ++k) { int t = wsum[k]; total += t; if (k < w) wpre += t; }
    int pre = carry + wpre + x - s;
    #pragma unroll
    for (int j = 0; j < 8; ++j) { int i = i0 + j; if (i < n) offsets[i] = pre + v[j]; }
    carry += total;
    __syncthreads();
  }
  if (tid == 0) offsets[n] = carry;
}

__global__ __launch_bounds__(256) void k_fill(const int* __restrict__ src, const int* __restrict__ dst,
                                              const int* __restrict__ offsets, int* __restrict__ cursor,
                                              int* __restrict__ ssrc, int E) {
  int e = blockIdx.x * 256 + threadIdx.x;
  if (e < E) {
    int d = dst[e];
    int pos = offsets[d] + atomicAdd(&cursor[d], 1);
    ssrc[pos] = src[e];
  }
}

// one wave per node; 4 x 16-lane groups, 16 edges (4 x 1KB gathers) in flight per iter;
// edge ids for up to 64 edges preloaded in one register, distributed via shfl.
__global__ __launch_bounds__(256) void k_aggregate_bf(const ushort* __restrict__ X, const int* __restrict__ offsets,
                                                      const int* __restrict__ ssrc, ushort* __restrict__ Agg, int n) {
  int wid = (blockIdx.x * 256 + threadIdx.x) >> 6;
  int lane = threadIdx.x & 63;
  if (wid >= n) return;
  int q = lane >> 4, r = lane & 15;
  int o0 = offsets[wid], deg = offsets[wid + 1] - o0;

  float acc[8];
  #pragma unroll
  for (int i = 0; i < 8; ++i) acc[i] = 0.f;

  for (int c0 = 0; c0 < deg; c0 += 64) {
    int cn = min(64, deg - c0);
    int myid = (lane < cn) ? ssrc[o0 + c0 + lane] : 0;
    for (int j = 0; j < cn; j += 16) {
      uint4 buf[4];
      #pragma unroll
      for (int t = 0; t < 4; ++t) {
        int e = j + t * 4 + q;
        buf[t] = (uint4){0u, 0u, 0u, 0u};
        if (e < cn) {
          int s = __shfl(myid, e);
          buf[t] = *(const uint4*)&X[(size_t)s * D + r * 8];
        }
      }
      #pragma unroll
      for (int t = 0; t < 4; ++t) {
        acc[0] += bf2f_lo(buf[t].x); acc[1] += bf2f_hi(buf[t].x);
        acc[2] += bf2f_lo(buf[t].y); acc[3] += bf2f_hi(buf[t].y);
        acc[4] += bf2f_lo(buf[t].z); acc[5] += bf2f_hi(buf[t].z);
        acc[6] += bf2f_lo(buf[t].w); acc[7] += bf2f_hi(buf[t].w);
      }
    }
  }
  #pragma unroll
  for (int i = 0; i < 8; ++i) {
    acc[i] += __shfl_xor(acc[i], 16);
    acc[i] += __shfl_xor(acc[i], 32);
  }
  if (q == 0) {
    float inv = 1.f / (float)max(deg, 1);
    uint4 o;
    o.x = (unsigned)f2bf(acc[0] * inv) | ((unsigned)f2bf(acc[1] * inv) << 16);
    o.y = (unsigned)f2bf(acc[2] * inv) | ((unsigned)f2bf(acc[3] * inv) << 16);
    o.z = (unsigned)f2bf(acc[4] * inv) | ((unsigned)f2bf(acc[5] * inv) << 16);
    o.w = (unsigned)f2bf(acc[6] * inv) | ((unsigned)f2bf(acc[7] * inv) << 16);
    *(uint4*)&Agg[(size_t)wid * D + r * 8] = o;
  }
}

// Out = relu(Agg @ Wl^T + Xin @ Wr^T + b), R6 config: block = 64 nodes,
// 4 waves in 2Mx2N grid (wave = 32 nodes x 64 outs, acc 2x4).
__global__ __launch_bounds__(256) void k_gemm_mfma(const ushort* __restrict__ Abf, const ushort* __restrict__ Xbf,
                                                   const ushort* __restrict__ Wl, const ushort* __restrict__ Wr,
                                                   const float* __restrict__ bias, ushort* __restrict__ Out, int n) {
  int tid = threadIdx.x;
  int wave = tid >> 6, lane = tid & 63;
  int wm = wave >> 1, wn = wave & 1;
  int m_base = blockIdx.x * 64 + wm * 32;
  int n_base = wn * 64;
  int r = lane & 15, kg = lane >> 4;

  f32x4 acc[2][4];
  #pragma unroll
  for (int i = 0; i < 2; ++i)
    #pragma unroll
    for (int j = 0; j < 4; ++j) acc[i][j] = (f32x4){0.f, 0.f, 0.f, 0.f};

  const ushort* As[2] = {Abf, Xbf};
  const ushort* Ws[2] = {Wl, Wr};
  #pragma unroll
  for (int half = 0; half < 2; ++half) {
    const ushort* A = As[half];
    const ushort* W = Ws[half];
    #pragma unroll
    for (int k0 = 0; k0 < 128; k0 += 32) {
      int kk = k0 + kg * 8;
      short8 a[2], b[4];
      #pragma unroll
      for (int fm = 0; fm < 2; ++fm)
        a[fm] = *(const short8*)&A[(size_t)(m_base + fm * 16 + r) * D + kk];
      #pragma unroll
      for (int fn = 0; fn < 4; ++fn)
        b[fn] = *(const short8*)&W[(size_t)(n_base + fn * 16 + r) * D + kk];
      #pragma unroll
      for (int fm = 0; fm < 2; ++fm)
        #pragma unroll
        for (int fn = 0; fn < 4; ++fn)
          acc[fm][fn] = __builtin_amdgcn_mfma_f32_16x16x32_bf16(a[fm], b[fn], acc[fm][fn], 0, 0, 0);
    }
  }
  #pragma unroll
  for (int fn = 0; fn < 4; ++fn) {
    int j = n_base + fn * 16 + r;
    float bj = bias[j];
    #pragma unroll
    for (int fm = 0; fm < 2; ++fm) {
      #pragma unroll
      for (int p = 0; p < 4; ++p) {
        int node = m_base + fm * 16 + kg * 4 + p;
        float v = fmaxf(acc[fm][fn][p] + bj, 0.f);
        Out[(size_t)node * D + j] = f2bf(v);
      }
    }
  }
}

__global__ __launch_bounds__(256) void k_pool_partial(const ushort* __restrict__ H, const int* __restrict__ batch,
                                                      float* __restrict__ partial, int n) {
  __shared__ float wsums[4][128];
  int g = blockIdx.x / PS, s = blockIdx.x % PS;
  int tid = threadIdx.x, wave = tid >> 6, lane = tid & 63;
  int a = 0, b = n;
  while (a < b) { int m = (a + b) >> 1; if (batch[m] < g) a = m + 1; else b = m; }
  int lo = a;
  b = n;
  while (a < b) { int m = (a + b) >> 1; if (batch[m] < g + 1) a = m + 1; else b = m; }
  int hi = a;
  int len = hi - lo;
  int chunk = (len + PS - 1) / PS;
  int a0 = lo + s * chunk;
  int a1 = min(a0 + chunk, hi);
  float ax = 0.f, ay = 0.f;
  for (int node = a0 + wave; node < a1; node += 4) {
    unsigned v = *(const unsigned*)&H[(size_t)node * D + lane * 2];
    ax += bf2f_lo(v);
    ay += bf2f_hi(v);
  }
  wsums[wave][lane * 2] = ax;
  wsums[wave][lane * 2 + 1] = ay;
  __syncthreads();
  if (tid < 128) {
    float v = wsums[0][tid] + wsums[1][tid] + wsums[2][tid] + wsums[3][tid];
    partial[(size_t)blockIdx.x * 128 + tid] = v;
  }
}

__global__ __launch_bounds__(256) void k_pool_fc2(const float* __restrict__ partial, const int* __restrict__ batch,
                                                  const float* __restrict__ Wfc, const float* __restrict__ bfc,
                                                  float* __restrict__ out, int n, int OUT) {
  __shared__ float pooled[128];
  int g = blockIdx.x;
  int tid = threadIdx.x, lane = tid & 63;
  int a = 0, b = n;
  while (a < b) { int m = (a + b) >> 1; if (batch[m] < g) a = m + 1; else b = m; }
  int lo = a;
  b = n;
  while (a < b) { int m = (a + b) >> 1; if (batch[m] < g + 1) a = m + 1; else b = m; }
  int hi = a;
  float inv = 1.f / (float)max(hi - lo, 1);
  if (tid < 128) {
    float v = 0.f;
    #pragma unroll
    for (int s = 0; s < PS; ++s) v += partial[(size_t)(g * PS + s) * 128 + tid];
    pooled[tid] = v * inv;
  }
  __syncthreads();
  if (tid < 64) {
    float2 p = *(const float2*)&pooled[lane * 2];
    for (int o = 0; o < OUT; ++o) {
      float2 w = *(const float2*)&Wfc[o * D + lane * 2];
      float part = p.x * w.x + p.y * w.y;
      #pragma unroll
      for (int off = 32; off > 0; off >>= 1) part += __shfl_down(part, off);
      if (lane == 0) out[g * OUT + o] = part + bfc[o];
    }
  }
}

extern "C" void kernel_launch(void* const* d_in, const int* in_sizes, int n_in,
                              void* d_out, int out_size, void* d_ws, size_t ws_size,
                              hipStream_t stream) {
  const float* x   = (const float*)d_in[0];
  const int* ei    = (const int*)d_in[1];
  const int* batch = (const int*)d_in[2];
  const float* W1l = (const float*)d_in[3];
  const float* W1r = (const float*)d_in[4];
  const float* b1  = (const float*)d_in[5];
  const float* W2l = (const float*)d_in[6];
  const float* W2r = (const float*)d_in[7];
  const float* b2  = (const float*)d_in[8];
  const float* W3l = (const float*)d_in[9];
  const float* W3r = (const float*)d_in[10];
  const float* b3  = (const float*)d_in[11];
  const float* Wfc = (const float*)d_in[12];
  const float* bfc = (const float*)d_in[13];
  float* out = (float*)d_out;

  int N = in_sizes[0] / D;
  int E = in_sizes[1] / 2;
  int OUT = in_sizes[12] / D;
  int G = out_size / OUT;
  const int* src = ei;
  const int* dst = ei + E;

  ushort* xb  = (ushort*)d_ws;
  ushort* agg = xb + (size_t)N * D;
  ushort* h1  = agg + (size_t)N * D;
  ushort* h2  = h1 + (size_t)N * D;
  ushort* wb  = h2 + (size_t)N * D;
  int* ssrc   = (int*)(wb + 6 * 128 * 128);
  int* hist   = ssrc + E;
  int* cursor = hist + N;          // adjacent to hist: one k_zero covers both
  int* offsets = cursor + N;
  float* partial = (float*)(offsets + N + 2);

  ushort* wl1 = wb + 0 * 16384; ushort* wr1 = wb + 1 * 16384;
  ushort* wl2 = wb + 2 * 16384; ushort* wr2 = wb + 3 * 16384;
  ushort* wl3 = wb + 4 * 16384; ushort* wr3 = wb + 5 * 16384;

  WPtrs wp;
  wp.s[0] = W1l; wp.s[1] = W1r; wp.s[2] = W2l; wp.s[3] = W2r; wp.s[4] = W3l; wp.s[5] = W3r;
  wp.d[0] = wl1; wp.d[1] = wr1; wp.d[2] = wl2; wp.d[3] = wr2; wp.d[4] = wl3; wp.d[5] = wr3;

  // zero hist+cursor: 2*N ints = N/2 uint4
  int n16 = (2 * N * 4) / 16;
  k_zero<<<(n16 + 255) / 256, 256, 0, stream>>>((uint4*)hist, n16);

  int n4 = N * D / 4;
  int nxb = (n4 + 255) / 256;
  int eb = (E + 255) / 256;
  k_prep<<<nxb + 96 + eb, 256, 0, stream>>>(x, xb, wp, dst, hist, n4, E);
  k_scan<<<1, 1024, 0, stream>>>(hist, offsets, N);
  k_fill<<<eb, 256, 0, stream>>>(src, dst, offsets, cursor, ssrc, E);

  int ab = (N * 64 + 255) / 256;
  int gb = (N + 63) / 64;

  k_aggregate_bf<<<ab, 256, 0, stream>>>(xb, offsets, ssrc, agg, N);
  k_gemm_mfma<<<gb, 256, 0, stream>>>(agg, xb, wl1, wr1, b1, h1, N);

  k_aggregate_bf<<<ab, 256, 0, stream>>>(h1, offsets, ssrc, agg, N);
  k_gemm_mfma<<<gb, 256, 0, stream>>>(agg, h1, wl2, wr2, b2, h2, N);

  k_aggregate_bf<<<ab, 256, 0, stream>>>(h2, offsets, ssrc, agg, N);
  k_gemm_mfma<<<gb, 256, 0, stream>>>(agg, h2, wl3, wr3, b3, h1, N);

  k_pool_partial<<<G * PS, 256, 0, stream>>>(h1, batch, partial, N);
  k_pool_fc2<<<G, 256, 0, stream>>>(partial, batch, Wfc, bfc, out, N, OUT);
}